// Round 10
// baseline (172.791 us; speedup 1.0000x reference)
//
#include <hip/hip_runtime.h>
#include <hip/hip_bf16.h>
#include <stdint.h>

#define EMB   2048
#define TOK   2048
#define NH    32
#define NKV   8
#define HD    64
#define QKVN  3072   // 2048 q + 512 k + 512 v

typedef __attribute__((ext_vector_type(8))) short bf16x8;   // 8 bf16 = 4 VGPRs
typedef __attribute__((ext_vector_type(4))) float f32x4;
typedef __attribute__((ext_vector_type(16))) float f32x16;
typedef __attribute__((ext_vector_type(4))) unsigned int u32x4;

__device__ __forceinline__ void gld16(const void* g, void* l) {
  auto gp = reinterpret_cast<const int __attribute__((address_space(1)))*>(
      reinterpret_cast<uintptr_t>(g));
  auto lp = reinterpret_cast<int __attribute__((address_space(3)))*>(
      reinterpret_cast<uintptr_t>(l));
  __builtin_amdgcn_global_load_lds(gp, lp, 16, 0, 0);
}

__device__ __forceinline__ unsigned int cvtpk_bf16(float lo, float hi) {
  unsigned int r;
  asm("v_cvt_pk_bf16_f32 %0, %1, %2" : "=v"(r) : "v"(lo), "v"(hi));
  return r;
}
// v_permlane32_swap_b32 — only ever used with distinct-value operands (P-relayout).
__device__ __forceinline__ void pl32swap(unsigned int &a, unsigned int &b) {
  asm volatile("v_permlane32_swap_b32 %0, %1" : "+v"(a), "+v"(b));
}
__device__ __forceinline__ float fexp2(float x) {  // v_exp_f32 IS 2^x
  float r;
  asm("v_exp_f32 %0, %1" : "=v"(r) : "v"(x));
  return r;
}

// ---------------------------------------------------------------- cast fp32->bf16
__global__ void cast_all(const float* __restrict__ x,  const float* __restrict__ wq,
                         const float* __restrict__ wk, const float* __restrict__ wv,
                         const float* __restrict__ wo,
                         __hip_bfloat16* __restrict__ xb,
                         __hip_bfloat16* __restrict__ wc,
                         __hip_bfloat16* __restrict__ wob) {
  const size_t M4 = (size_t)4 * 1024 * 1024;
  const size_t M1 = (size_t)1024 * 1024;
  size_t i = ((size_t)blockIdx.x * 256 + threadIdx.x) * 4;
  const float* src;
  __hip_bfloat16* dst;
  if (i < M4)                    { src = x  + i;                 dst = xb  + i; }
  else if (i < 2*M4)             { src = wq + (i - M4);          dst = wc  + (i - M4); }
  else if (i < 2*M4 + M1)        { src = wk + (i - 2*M4);        dst = wc  + M4 + (i - 2*M4); }
  else if (i < 2*M4 + 2*M1)      { src = wv + (i - 2*M4 - M1);   dst = wc  + M4 + M1 + (i - 2*M4 - M1); }
  else                           { src = wo + (i - 2*M4 - 2*M1); dst = wob + (i - 2*M4 - 2*M1); }
  float4 v = *reinterpret_cast<const float4*>(src);
  dst[0] = __float2bfloat16(v.x);
  dst[1] = __float2bfloat16(v.y);
  dst[2] = __float2bfloat16(v.z);
  dst[3] = __float2bfloat16(v.w);
}

// ---------------------------------------------------------------- GEMM  C = A * B^T
// Counted-vmcnt 3-slot schedule (T3+T4), (row&7)<<4 XOR swizzle (T2), 8 waves.
template<int BN>
__global__ __launch_bounds__(512) void gemm8(const __hip_bfloat16* __restrict__ A,
                                             const __hip_bfloat16* __restrict__ B,
                                             float* __restrict__ C,
                                             int M, int N, int K) {
  constexpr int A_BYTES = 128 * 128;        // 16 KB
  constexpr int B_BYTES = BN * 128;
  constexpr int SLOT    = A_BYTES + B_BYTES;
  constexpr int CA = 2;
  constexpr int CB = BN / 64;
  constexpr int NR = BN / 64;
  extern __shared__ char lds[];             // 3 * SLOT

  const int nbc = N / BN;
  const int nwg = gridDim.x;
  int bid = blockIdx.x;
  bid = (bid & 7) * (nwg >> 3) + (bid >> 3);   // bijective XCD swizzle
  const int br = bid / nbc, bc = bid % nbc;

  const int tid  = threadIdx.x;
  const int w    = tid >> 6;
  const int lane = tid & 63;
  const int wr   = w >> 2, wc = w & 3;
  const int l15  = lane & 15, lg = lane >> 4;
  const int axor = (l15 & 7) << 4;

  const __hip_bfloat16* Ag = A + (size_t)br * 128 * K;
  const __hip_bfloat16* Bg = B + (size_t)bc * BN * K;

  const int srow = lane >> 3;
  const int scol = (((lane & 7) ^ srow) << 3);

  auto stageA = [&](char* slot, int kt) {
#pragma unroll
    for (int i = 0; i < CA; ++i) {
      const int c = w * CA + i;
      gld16(Ag + (size_t)(c * 8 + srow) * K + kt + scol, slot + c * 1024);
    }
  };
  auto stageB = [&](char* slot, int kt) {
#pragma unroll
    for (int i = 0; i < CB; ++i) {
      const int c = w * CB + i;
      gld16(Bg + (size_t)(c * 8 + srow) * K + kt + scol, slot + A_BYTES + c * 1024);
    }
  };
  auto ldA = [&](const char* sa, int m, int kk) {
    return *reinterpret_cast<const bf16x8*>(
        sa + (wr * 64 + m * 16 + l15) * 128 + ((kk * 64 + lg * 16) ^ axor));
  };
  auto ldB = [&](const char* sa, int n, int kk) {
    return *reinterpret_cast<const bf16x8*>(
        sa + A_BYTES + (wc * (BN / 4) + n * 16 + l15) * 128 + ((kk * 64 + lg * 16) ^ axor));
  };

  f32x4 acc[4][NR];
#pragma unroll
  for (int m = 0; m < 4; ++m)
#pragma unroll
    for (int n = 0; n < NR; ++n) acc[m][n] = (f32x4){0.f, 0.f, 0.f, 0.f};

  const int nt = K >> 6;

  stageA(lds, 0);         stageB(lds, 0);
  stageA(lds + SLOT, 64); stageB(lds + SLOT, 64);
  if constexpr (CA + CB == 4) asm volatile("s_waitcnt vmcnt(4)" ::: "memory");
  else                        asm volatile("s_waitcnt vmcnt(5)" ::: "memory");
  __builtin_amdgcn_s_barrier();

  int slc = 0, sls = 2;
  for (int t = 0; t < nt; ++t) {
    const char* sa = lds + slc * SLOT;
    char* stg = lds + sls * SLOT;
    const bool do_stage = (t + 2) < nt;
    const int kt2 = (t + 2) << 6;

    bf16x8 afr[2][2], bfr[NR][2];
#pragma unroll
    for (int m = 0; m < 2; ++m)
#pragma unroll
      for (int kk = 0; kk < 2; ++kk) afr[m][kk] = ldA(sa, m, kk);
#pragma unroll
    for (int n = 0; n < NR; ++n)
#pragma unroll
      for (int kk = 0; kk < 2; ++kk) bfr[n][kk] = ldB(sa, n, kk);
    if (do_stage) stageA(stg, kt2);
    __builtin_amdgcn_s_barrier();
    asm volatile("s_waitcnt lgkmcnt(0)" ::: "memory");
    __builtin_amdgcn_sched_barrier(0);
    __builtin_amdgcn_s_setprio(1);
#pragma unroll
    for (int m = 0; m < 2; ++m)
#pragma unroll
      for (int n = 0; n < NR; ++n)
#pragma unroll
        for (int kk = 0; kk < 2; ++kk)
          acc[m][n] = __builtin_amdgcn_mfma_f32_16x16x32_bf16(afr[m][kk], bfr[n][kk],
                                                              acc[m][n], 0, 0, 0);
    __builtin_amdgcn_s_setprio(0);
    __builtin_amdgcn_s_barrier();

#pragma unroll
    for (int m = 0; m < 2; ++m)
#pragma unroll
      for (int kk = 0; kk < 2; ++kk) afr[m][kk] = ldA(sa, 2 + m, kk);
    if (do_stage) stageB(stg, kt2);
    __builtin_amdgcn_s_barrier();
    asm volatile("s_waitcnt lgkmcnt(0)" ::: "memory");
    __builtin_amdgcn_sched_barrier(0);
    __builtin_amdgcn_s_setprio(1);
#pragma unroll
    for (int m = 0; m < 2; ++m)
#pragma unroll
      for (int n = 0; n < NR; ++n)
#pragma unroll
        for (int kk = 0; kk < 2; ++kk)
          acc[2 + m][n] = __builtin_amdgcn_mfma_f32_16x16x32_bf16(afr[m][kk], bfr[n][kk],
                                                                  acc[2 + m][n], 0, 0, 0);
    __builtin_amdgcn_s_setprio(0);
    if (t < nt - 2) {
      if constexpr (CA + CB == 4) asm volatile("s_waitcnt vmcnt(4)" ::: "memory");
      else                        asm volatile("s_waitcnt vmcnt(5)" ::: "memory");
    } else {
      asm volatile("s_waitcnt vmcnt(0)" ::: "memory");
    }
    __builtin_amdgcn_s_barrier();

    slc = (slc == 2) ? 0 : slc + 1;
    sls = (sls == 2) ? 0 : sls + 1;
  }

  const int row0 = br * 128 + wr * 64;
  const int col0 = bc * BN + wc * (BN / 4);
#pragma unroll
  for (int m = 0; m < 4; ++m)
#pragma unroll
    for (int n = 0; n < NR; ++n)
#pragma unroll
      for (int r = 0; r < 4; ++r)
        C[(size_t)(row0 + m * 16 + lg * 4 + r) * N + col0 + n * 16 + l15] = acc[m][n][r];
}

// ---------------------------------------------------------------- RoPE + cast to tiled fragment layouts
#define QSCALE 0.1803368801111243f   // 0.125 * log2(e)

__device__ __forceinline__ size_t kq_idx(int tile_row, int t, int d) {
  return ((size_t)tile_row) * 2048 +
         ((((d >> 4) * 64) + (((d >> 3) & 1) * 32) + (t & 31)) << 3) + (d & 7);
}

__global__ void rope_cast(const float* __restrict__ qkv,
                          const float* __restrict__ cosT, const float* __restrict__ sinT,
                          __hip_bfloat16* __restrict__ Qf,
                          __hip_bfloat16* __restrict__ Kf,
                          __hip_bfloat16* __restrict__ Vf) {
  const int QP = TOK * NH * (HD / 2);   // 2,097,152
  const int KP = TOK * NKV * (HD / 2);  //   524,288
  int idx = blockIdx.x * 256 + threadIdx.x;
  if (idx < QP) {
    int d = idx & 31, h = (idx >> 5) & 31, t = idx >> 10;
    const float* row = qkv + (size_t)t * QKVN + h * 64;
    float x1 = row[d], x2 = row[d + 32];
    float o1 = (x1 * cosT[t * 64 + d]      - x2 * sinT[t * 64 + d])      * QSCALE;
    float o2 = (x2 * cosT[t * 64 + d + 32] + x1 * sinT[t * 64 + d + 32]) * QSCALE;
    const int tile_row = h * 64 + (t >> 5);
    Qf[kq_idx(tile_row, t, d)]      = __float2bfloat16(o1);
    Qf[kq_idx(tile_row, t, d + 32)] = __float2bfloat16(o2);
  } else if (idx < QP + KP) {
    int j = idx - QP;
    int d = j & 31, hk = (j >> 5) & 7, t = j >> 8;
    const float* row = qkv + (size_t)t * QKVN + 2048 + hk * 64;
    float x1 = row[d], x2 = row[d + 32];
    float o1 = x1 * cosT[t * 64 + d]      - x2 * sinT[t * 64 + d];
    float o2 = x2 * cosT[t * 64 + d + 32] + x1 * sinT[t * 64 + d + 32];
    const int tile_row = hk * 64 + (t >> 5);
    Kf[kq_idx(tile_row, t, d)]      = __float2bfloat16(o1);
    Kf[kq_idx(tile_row, t, d + 32)] = __float2bfloat16(o2);
  } else {
    int vj = idx - QP - KP;               // d fastest -> coalesced qkv reads
    int d = vj & 63, t = (vj >> 6) & (TOK - 1), hk = vj >> 17;
    float v = qkv[(size_t)t * QKVN + 2560 + hk * 64 + d];
    const size_t tb = ((size_t)hk * 64 + (t >> 5)) * 2048;
    const int c = (((t >> 4) & 1) * 128) + ((d >> 5) * 64) + (((t >> 3) & 1) * 32) + (d & 31);
    Vf[tb + (c << 3) + (t & 7)] = __float2bfloat16(v);
  }
}

// ---------------------------------------------------------------- causal GQA flash attention
// Uniform work units (flash-decoding): each 1-wave block processes <=16 kv-tiles
// of one (head, strip) and writes a bf16-packed partial (O^T, m, l) to scratch;
// a merge kernel combines <=4 partials per (head, strip). Units per strip:
// ceil((s+1)/16) -> 160/head, 5120 blocks total, all near-uniform.
#define MBIAS 10.0f
#define UPH   160   // units per head

struct KVb { bf16x8 k0, k1, k2, k3, v00, v01, v10, v11; };

__device__ __forceinline__ void load_kv(KVb& b, const __hip_bfloat16* Kt,
                                        const __hip_bfloat16* Vt, int tile,
                                        int lane) {
  const __hip_bfloat16* Kp = Kt + (size_t)tile * 2048 + lane * 8;
  b.k0 = *reinterpret_cast<const bf16x8*>(Kp);
  b.k1 = *reinterpret_cast<const bf16x8*>(Kp + 512);
  b.k2 = *reinterpret_cast<const bf16x8*>(Kp + 1024);
  b.k3 = *reinterpret_cast<const bf16x8*>(Kp + 1536);
  const __hip_bfloat16* Vp = Vt + (size_t)tile * 2048 + lane * 8;
  b.v00 = *reinterpret_cast<const bf16x8*>(Vp);
  b.v10 = *reinterpret_cast<const bf16x8*>(Vp + 512);
  b.v01 = *reinterpret_cast<const bf16x8*>(Vp + 1024);
  b.v11 = *reinterpret_cast<const bf16x8*>(Vp + 1536);
}

__device__ __forceinline__ void compute_tile(const KVb& b, bool diag,
                                             const bf16x8 (&qf)[4],
                                             const f32x16& minit,
                                             int l31, int hi,
                                             float& mb, float& l,
                                             f32x16& oa0, f32x16& oa1) {
  // S^T = K Q^T - MBIAS (bias folded into C operand)
  __builtin_amdgcn_s_setprio(1);
  f32x16 st = __builtin_amdgcn_mfma_f32_32x32x16_bf16(b.k0, qf[0], minit, 0, 0, 0);
  st = __builtin_amdgcn_mfma_f32_32x32x16_bf16(b.k1, qf[1], st, 0, 0, 0);
  st = __builtin_amdgcn_mfma_f32_32x32x16_bf16(b.k2, qf[2], st, 0, 0, 0);
  st = __builtin_amdgcn_mfma_f32_32x32x16_bf16(b.k3, qf[3], st, 0, 0, 0);
  __builtin_amdgcn_s_setprio(0);

  float s[16];
#pragma unroll
  for (int r = 0; r < 16; ++r) s[r] = st[r];
  if (diag) {
#pragma unroll
    for (int r = 0; r < 16; ++r) {
      const int crow = (r & 3) + 8 * (r >> 2) + 4 * hi;
      s[r] = (crow <= l31) ? s[r] : -1e30f;
    }
  }
  float a0 = fmaxf(fmaxf(s[0], s[1]),  s[2]);
  float a1 = fmaxf(fmaxf(s[3], s[4]),  s[5]);
  float a2 = fmaxf(fmaxf(s[6], s[7]),  s[8]);
  float a3 = fmaxf(fmaxf(s[9], s[10]), s[11]);
  float a4 = fmaxf(fmaxf(s[12], s[13]), s[14]);
  float rmax = fmaxf(fmaxf(fmaxf(fmaxf(a0, a1), a2), fmaxf(a3, a4)), s[15]);
  rmax = fmaxf(rmax, __shfl_xor(rmax, 32));

  if (!__all(rmax <= mb + 8.0f)) {      // rescale path: ~never taken w/ this data
    const float mnew = fmaxf(mb, rmax);
    const float resc = fexp2(mb - mnew);
    l *= resc;
#pragma unroll
    for (int r = 0; r < 16; ++r) { oa0[r] *= resc; oa1[r] *= resc; }
    mb = mnew;
  }

  float p[16];
  if (mb == 0.0f) {                     // fast path: bias already folded
#pragma unroll
    for (int r = 0; r < 16; ++r) p[r] = fexp2(s[r]);
  } else {
#pragma unroll
    for (int r = 0; r < 16; ++r) p[r] = fexp2(s[r] - mb);
  }
  float u0 = (p[0] + p[1]) + (p[2] + p[3]);
  float u1 = (p[4] + p[5]) + (p[6] + p[7]);
  float u2 = (p[8] + p[9]) + (p[10] + p[11]);
  float u3 = (p[12] + p[13]) + (p[14] + p[15]);
  float rsum = (u0 + u1) + (u2 + u3);
  rsum += __shfl_xor(rsum, 32);
  l += rsum;

  unsigned int wpk[8];
#pragma unroll
  for (int j = 0; j < 8; ++j) wpk[j] = cvtpk_bf16(p[2 * j], p[2 * j + 1]);

  __builtin_amdgcn_s_setprio(1);
  {
    unsigned int x0 = wpk[0], y0 = wpk[2];  pl32swap(x0, y0);
    unsigned int x1 = wpk[1], y1 = wpk[3];  pl32swap(x1, y1);
    u32x4 pw; pw[0] = x0; pw[1] = x1; pw[2] = y0; pw[3] = y1;
    bf16x8 pf = *reinterpret_cast<bf16x8*>(&pw);
    oa0 = __builtin_amdgcn_mfma_f32_32x32x16_bf16(b.v00, pf, oa0, 0, 0, 0);
    oa1 = __builtin_amdgcn_mfma_f32_32x32x16_bf16(b.v10, pf, oa1, 0, 0, 0);
  }
  {
    unsigned int x0 = wpk[4], y0 = wpk[6];  pl32swap(x0, y0);
    unsigned int x1 = wpk[5], y1 = wpk[7];  pl32swap(x1, y1);
    u32x4 pw; pw[0] = x0; pw[1] = x1; pw[2] = y0; pw[3] = y1;
    bf16x8 pf = *reinterpret_cast<bf16x8*>(&pw);
    oa0 = __builtin_amdgcn_mfma_f32_32x32x16_bf16(b.v01, pf, oa0, 0, 0, 0);
    oa1 = __builtin_amdgcn_mfma_f32_32x32x16_bf16(b.v11, pf, oa1, 0, 0, 0);
  }
  __builtin_amdgcn_s_setprio(0);
}

// grid = 32 heads * 160 units (desc); block = 64 (1 wave).
// po: [slot][q][d0] packed bf16 pairs (lo=d0, hi=d0+32), slot = h*UPH + fu.
// pml: [slot][0..31]=m, [slot][32..63]=l.
__global__ __launch_bounds__(64) void attn7(const __hip_bfloat16* __restrict__ Qf,
                                            const __hip_bfloat16* __restrict__ Kf,
                                            const __hip_bfloat16* __restrict__ Vf,
                                            unsigned int* __restrict__ po,
                                            float* __restrict__ pml) {
  const int h  = blockIdx.x & 31;
  const int fu = (UPH - 1) - (blockIdx.x >> 5);   // descending: full chunks first
  // decode fu -> (strip s, chunk c); fu = base(s) + c
  int s, c;
  if (fu < 16)      { s = fu; c = 0; }
  else if (fu < 48) { int q = fu - 16; s = 16 + (q >> 1); c = q & 1; }
  else if (fu < 96) { int q = fu - 48; int d3 = q / 3; s = 32 + d3; c = q - 3 * d3; }
  else              { int q = fu - 96; s = 48 + (q >> 2); c = q & 3; }
  const int hk   = h >> 2;
  const int lane = threadIdx.x;
  const int l31  = lane & 31, hi = lane >> 5;
  const int nt   = s + 1;                 // total kv tiles for this strip
  const int t0   = c * 16;
  const int t1   = (t0 + 16 < nt) ? t0 + 16 : nt;

  __shared__ unsigned int T[32][33];      // partial transpose staging (padded)

  const __hip_bfloat16* Kt = Kf + (size_t)hk * 64 * 2048;
  const __hip_bfloat16* Vt = Vf + (size_t)hk * 64 * 2048;

  const __hip_bfloat16* Qp = Qf + ((size_t)h * 64 + s) * 2048 + lane * 8;
  bf16x8 qf[4];
#pragma unroll
  for (int ks = 0; ks < 4; ++ks)
    qf[ks] = *reinterpret_cast<const bf16x8*>(Qp + ks * 512);

  f32x16 minit;
#pragma unroll
  for (int r = 0; r < 16; ++r) minit[r] = -MBIAS;

  f32x16 oa0, oa1;
#pragma unroll
  for (int r = 0; r < 16; ++r) { oa0[r] = 0.f; oa1[r] = 0.f; }
  float mb = 0.f, l = 0.f;

  KVb A, B;
  load_kv(A, Kt, Vt, t0, lane);
  int t = t0;
  for (;;) {
    int nx = t + 1;
    if (nx < t1) load_kv(B, Kt, Vt, nx, lane);
    compute_tile(A, t == nt - 1, qf, minit, l31, hi, mb, l, oa0, oa1);
    t = nx;
    if (t >= t1) break;
    nx = t + 1;
    if (nx < t1) load_kv(A, Kt, Vt, nx, lane);
    compute_tile(B, t == nt - 1, qf, minit, l31, hi, mb, l, oa0, oa1);
    t = nx;
    if (t >= t1) break;
  }

  // ---- partial out: pack bf16 pairs, transpose via LDS, coalesced global write
  const int slot = h * UPH + fu;
#pragma unroll
  for (int r = 0; r < 16; ++r) {
    const int d0 = (r & 3) + 8 * (r >> 2) + 4 * hi;   // 0..31
    T[d0][l31] = cvtpk_bf16(oa0[r], oa1[r]);
  }
  // single wave: compiler inserts lgkmcnt for same-wave LDS RAW
  unsigned int* slotp = po + (size_t)slot * 1024;     // [q][d0]
#pragma unroll
  for (int k = 0; k < 16; ++k) {
    const int idx = k * 64 + lane;                    // q = idx>>5, d0 = idx&31
    slotp[idx] = T[idx & 31][idx >> 5];
  }
  if (hi == 0) {
    pml[slot * 64 + l31]      = mb;
    pml[slot * 64 + 32 + l31] = l;
  }
}

// merge: grid = 32 heads * 64 strips; block = 64 (lane = d). <=4 partials.
__global__ __launch_bounds__(64) void attn_merge(const unsigned int* __restrict__ po,
                                                 const float* __restrict__ pml,
                                                 __hip_bfloat16* __restrict__ ctx) {
  const int h = blockIdx.x & 31;
  const int s = blockIdx.x >> 5;
  const int d = threadIdx.x;
  const int nu  = (s >> 4) + 1;
  const int seg = s >> 4;
  const int base = (seg == 0) ? s
                 : (seg == 1) ? 16 + (s - 16) * 2
                 : (seg == 2) ? 48 + (s - 32) * 3
                 :              96 + (s - 48) * 4;
  const int slot0 = h * UPH + base;

  for (int q = 0; q < 32; ++q) {
    float mm[4], ll[4];
    float M = -1e30f;
    for (int u = 0; u < nu; ++u) {
      mm[u] = pml[(slot0 + u) * 64 + q];
      ll[u] = pml[(slot0 + u) * 64 + 32 + q];
      M = fmaxf(M, mm[u]);
    }
    float L = 0.f, val = 0.f;
    for (int u = 0; u < nu; ++u) {
      const float sc = fexp2(mm[u] - M);
      L += ll[u] * sc;
      const unsigned int pu = po[(size_t)(slot0 + u) * 1024 + q * 32 + (d & 31)];
      const unsigned int wv = (d < 32) ? (pu << 16) : (pu & 0xffff0000u);
      val += __uint_as_float(wv) * sc;
    }
    ctx[(size_t)(s * 32 + q) * EMB + h * HD + d] = __float2bfloat16(val / L);
  }
}

// ---------------------------------------------------------------- launch
extern "C" void kernel_launch(void* const* d_in, const int* in_sizes, int n_in,
                              void* d_out, int out_size, void* d_ws, size_t ws_size,
                              hipStream_t stream) {
  const float* x    = (const float*)d_in[0];
  const float* cosT = (const float*)d_in[1];
  const float* sinT = (const float*)d_in[2];
  const float* Wq   = (const float*)d_in[3];
  const float* Wk   = (const float*)d_in[4];
  const float* Wv   = (const float*)d_in[5];
  const float* Wo   = (const float*)d_in[6];
  float* out = (float*)d_out;

  const size_t M4 = (size_t)4 * 1024 * 1024;
  const size_t M1 = (size_t)1024 * 1024;

  char* ws = (char*)d_ws;
  __hip_bfloat16* xb   = (__hip_bfloat16*)ws;
  __hip_bfloat16* Wc   = xb + M4;
  __hip_bfloat16* Wob  = Wc + (size_t)6 * M1;
  float*          qkv  = (float*)(Wob + M4);          // 24 MB; dead after rope_cast
  __hip_bfloat16* Qf   = (__hip_bfloat16*)(qkv + (size_t)TOK * QKVN);
  __hip_bfloat16* Kf   = Qf + (size_t)NH * TOK * HD;
  __hip_bfloat16* Vf   = Kf + (size_t)NKV * TOK * HD;
  __hip_bfloat16* ctxb = Vf + (size_t)NKV * HD * TOK;

  // attention partials alias the dead qkv region (22.3 MB <= 24 MB)
  unsigned int* po  = (unsigned int*)qkv;             // 5120 * 1024 u32 = 21.0 MB
  float*        pml = (float*)(po + (size_t)32 * UPH * 1024);  // 5120*64 f32 = 1.3 MB

  constexpr int SLOT192 = 128 * 128 + 192 * 128;
  constexpr int SLOT128 = 128 * 128 + 128 * 128;
  hipFuncSetAttribute(reinterpret_cast<const void*>(&gemm8<192>),
                      hipFuncAttributeMaxDynamicSharedMemorySize, 3 * SLOT192);
  hipFuncSetAttribute(reinterpret_cast<const void*>(&gemm8<128>),
                      hipFuncAttributeMaxDynamicSharedMemorySize, 3 * SLOT128);

  cast_all<<<14336, 256, 0, stream>>>(x, Wq, Wk, Wv, Wo, xb, Wc, Wob);

  // qkv = x @ Wqkv^T   (M=2048, N=3072, K=2048): 256 blocks
  gemm8<192><<<256, 512, 3 * SLOT192, stream>>>(xb, Wc, qkv, TOK, QKVN, EMB);

  rope_cast<<<14336, 256, 0, stream>>>(qkv, cosT, sinT, Qf, Kf, Vf);

  // causal GQA attention: uniform units -> partials, then merge
  attn7<<<32 * UPH, 64, 0, stream>>>(Qf, Kf, Vf, po, pml);
  attn_merge<<<32 * 64, 64, 0, stream>>>(po, pml, ctxb);

  // out = ctx @ Wo^T   (M=N=K=2048): 256 blocks
  gemm8<128><<<256, 512, 3 * SLOT128, stream>>>(ctxb, Wob, out, TOK, EMB, EMB);
}

// Round 11
// 143.984 us; speedup vs baseline: 1.2001x; 1.2001x over previous
//
#include <hip/hip_runtime.h>
#include <hip/hip_bf16.h>
#include <stdint.h>

#define EMB   2048
#define TOK   2048
#define NH    32
#define NKV   8
#define HD    64
#define QKVN  3072   // 2048 q + 512 k + 512 v

typedef __attribute__((ext_vector_type(8))) short bf16x8;   // 8 bf16 = 4 VGPRs
typedef __attribute__((ext_vector_type(4))) float f32x4;
typedef __attribute__((ext_vector_type(16))) float f32x16;
typedef __attribute__((ext_vector_type(4))) unsigned int u32x4;

__device__ __forceinline__ void gld16(const void* g, void* l) {
  auto gp = reinterpret_cast<const int __attribute__((address_space(1)))*>(
      reinterpret_cast<uintptr_t>(g));
  auto lp = reinterpret_cast<int __attribute__((address_space(3)))*>(
      reinterpret_cast<uintptr_t>(l));
  __builtin_amdgcn_global_load_lds(gp, lp, 16, 0, 0);
}

__device__ __forceinline__ unsigned int cvtpk_bf16(float lo, float hi) {
  unsigned int r;
  asm("v_cvt_pk_bf16_f32 %0, %1, %2" : "=v"(r) : "v"(lo), "v"(hi));
  return r;
}
// v_permlane32_swap_b32 — only ever used with distinct-value operands (P-relayout).
__device__ __forceinline__ void pl32swap(unsigned int &a, unsigned int &b) {
  asm volatile("v_permlane32_swap_b32 %0, %1" : "+v"(a), "+v"(b));
}
__device__ __forceinline__ float fexp2(float x) {  // v_exp_f32 IS 2^x
  float r;
  asm("v_exp_f32 %0, %1" : "=v"(r) : "v"(x));
  return r;
}

// ---------------------------------------------------------------- cast fp32->bf16
__global__ void cast_all(const float* __restrict__ x,  const float* __restrict__ wq,
                         const float* __restrict__ wk, const float* __restrict__ wv,
                         const float* __restrict__ wo,
                         __hip_bfloat16* __restrict__ xb,
                         __hip_bfloat16* __restrict__ wc,
                         __hip_bfloat16* __restrict__ wob) {
  const size_t M4 = (size_t)4 * 1024 * 1024;
  const size_t M1 = (size_t)1024 * 1024;
  size_t i = ((size_t)blockIdx.x * 256 + threadIdx.x) * 4;
  const float* src;
  __hip_bfloat16* dst;
  if (i < M4)                    { src = x  + i;                 dst = xb  + i; }
  else if (i < 2*M4)             { src = wq + (i - M4);          dst = wc  + (i - M4); }
  else if (i < 2*M4 + M1)        { src = wk + (i - 2*M4);        dst = wc  + M4 + (i - 2*M4); }
  else if (i < 2*M4 + 2*M1)      { src = wv + (i - 2*M4 - M1);   dst = wc  + M4 + M1 + (i - 2*M4 - M1); }
  else                           { src = wo + (i - 2*M4 - 2*M1); dst = wob + (i - 2*M4 - 2*M1); }
  float4 v = *reinterpret_cast<const float4*>(src);
  dst[0] = __float2bfloat16(v.x);
  dst[1] = __float2bfloat16(v.y);
  dst[2] = __float2bfloat16(v.z);
  dst[3] = __float2bfloat16(v.w);
}

// ---------------------------------------------------------------- GEMM  C = A * B^T
// Counted-vmcnt 3-slot schedule (T3+T4), (row&7)<<4 XOR swizzle (T2), 8 waves.
template<int BN>
__global__ __launch_bounds__(512) void gemm8(const __hip_bfloat16* __restrict__ A,
                                             const __hip_bfloat16* __restrict__ B,
                                             float* __restrict__ C,
                                             int M, int N, int K) {
  constexpr int A_BYTES = 128 * 128;        // 16 KB
  constexpr int B_BYTES = BN * 128;
  constexpr int SLOT    = A_BYTES + B_BYTES;
  constexpr int CA = 2;
  constexpr int CB = BN / 64;
  constexpr int NR = BN / 64;
  extern __shared__ char lds[];             // 3 * SLOT

  const int nbc = N / BN;
  const int nwg = gridDim.x;
  int bid = blockIdx.x;
  bid = (bid & 7) * (nwg >> 3) + (bid >> 3);   // bijective XCD swizzle
  const int br = bid / nbc, bc = bid % nbc;

  const int tid  = threadIdx.x;
  const int w    = tid >> 6;
  const int lane = tid & 63;
  const int wr   = w >> 2, wc = w & 3;
  const int l15  = lane & 15, lg = lane >> 4;
  const int axor = (l15 & 7) << 4;

  const __hip_bfloat16* Ag = A + (size_t)br * 128 * K;
  const __hip_bfloat16* Bg = B + (size_t)bc * BN * K;

  const int srow = lane >> 3;
  const int scol = (((lane & 7) ^ srow) << 3);

  auto stageA = [&](char* slot, int kt) {
#pragma unroll
    for (int i = 0; i < CA; ++i) {
      const int c = w * CA + i;
      gld16(Ag + (size_t)(c * 8 + srow) * K + kt + scol, slot + c * 1024);
    }
  };
  auto stageB = [&](char* slot, int kt) {
#pragma unroll
    for (int i = 0; i < CB; ++i) {
      const int c = w * CB + i;
      gld16(Bg + (size_t)(c * 8 + srow) * K + kt + scol, slot + A_BYTES + c * 1024);
    }
  };
  auto ldA = [&](const char* sa, int m, int kk) {
    return *reinterpret_cast<const bf16x8*>(
        sa + (wr * 64 + m * 16 + l15) * 128 + ((kk * 64 + lg * 16) ^ axor));
  };
  auto ldB = [&](const char* sa, int n, int kk) {
    return *reinterpret_cast<const bf16x8*>(
        sa + A_BYTES + (wc * (BN / 4) + n * 16 + l15) * 128 + ((kk * 64 + lg * 16) ^ axor));
  };

  f32x4 acc[4][NR];
#pragma unroll
  for (int m = 0; m < 4; ++m)
#pragma unroll
    for (int n = 0; n < NR; ++n) acc[m][n] = (f32x4){0.f, 0.f, 0.f, 0.f};

  const int nt = K >> 6;

  stageA(lds, 0);         stageB(lds, 0);
  stageA(lds + SLOT, 64); stageB(lds + SLOT, 64);
  if constexpr (CA + CB == 4) asm volatile("s_waitcnt vmcnt(4)" ::: "memory");
  else                        asm volatile("s_waitcnt vmcnt(5)" ::: "memory");
  __builtin_amdgcn_s_barrier();

  int slc = 0, sls = 2;
  for (int t = 0; t < nt; ++t) {
    const char* sa = lds + slc * SLOT;
    char* stg = lds + sls * SLOT;
    const bool do_stage = (t + 2) < nt;
    const int kt2 = (t + 2) << 6;

    bf16x8 afr[2][2], bfr[NR][2];
#pragma unroll
    for (int m = 0; m < 2; ++m)
#pragma unroll
      for (int kk = 0; kk < 2; ++kk) afr[m][kk] = ldA(sa, m, kk);
#pragma unroll
    for (int n = 0; n < NR; ++n)
#pragma unroll
      for (int kk = 0; kk < 2; ++kk) bfr[n][kk] = ldB(sa, n, kk);
    if (do_stage) stageA(stg, kt2);
    __builtin_amdgcn_s_barrier();
    asm volatile("s_waitcnt lgkmcnt(0)" ::: "memory");
    __builtin_amdgcn_sched_barrier(0);
    __builtin_amdgcn_s_setprio(1);
#pragma unroll
    for (int m = 0; m < 2; ++m)
#pragma unroll
      for (int n = 0; n < NR; ++n)
#pragma unroll
        for (int kk = 0; kk < 2; ++kk)
          acc[m][n] = __builtin_amdgcn_mfma_f32_16x16x32_bf16(afr[m][kk], bfr[n][kk],
                                                              acc[m][n], 0, 0, 0);
    __builtin_amdgcn_s_setprio(0);
    __builtin_amdgcn_s_barrier();

#pragma unroll
    for (int m = 0; m < 2; ++m)
#pragma unroll
      for (int kk = 0; kk < 2; ++kk) afr[m][kk] = ldA(sa, 2 + m, kk);
    if (do_stage) stageB(stg, kt2);
    __builtin_amdgcn_s_barrier();
    asm volatile("s_waitcnt lgkmcnt(0)" ::: "memory");
    __builtin_amdgcn_sched_barrier(0);
    __builtin_amdgcn_s_setprio(1);
#pragma unroll
    for (int m = 0; m < 2; ++m)
#pragma unroll
      for (int n = 0; n < NR; ++n)
#pragma unroll
        for (int kk = 0; kk < 2; ++kk)
          acc[2 + m][n] = __builtin_amdgcn_mfma_f32_16x16x32_bf16(afr[m][kk], bfr[n][kk],
                                                                  acc[2 + m][n], 0, 0, 0);
    __builtin_amdgcn_s_setprio(0);
    if (t < nt - 2) {
      if constexpr (CA + CB == 4) asm volatile("s_waitcnt vmcnt(4)" ::: "memory");
      else                        asm volatile("s_waitcnt vmcnt(5)" ::: "memory");
    } else {
      asm volatile("s_waitcnt vmcnt(0)" ::: "memory");
    }
    __builtin_amdgcn_s_barrier();

    slc = (slc == 2) ? 0 : slc + 1;
    sls = (sls == 2) ? 0 : sls + 1;
  }

  const int row0 = br * 128 + wr * 64;
  const int col0 = bc * BN + wc * (BN / 4);
#pragma unroll
  for (int m = 0; m < 4; ++m)
#pragma unroll
    for (int n = 0; n < NR; ++n)
#pragma unroll
      for (int r = 0; r < 4; ++r)
        C[(size_t)(row0 + m * 16 + lg * 4 + r) * N + col0 + n * 16 + l15] = acc[m][n][r];
}

// ---------------------------------------------------------------- RoPE + cast to tiled fragment layouts
#define QSCALE 0.1803368801111243f   // 0.125 * log2(e)

__device__ __forceinline__ size_t kq_idx(int tile_row, int t, int d) {
  return ((size_t)tile_row) * 2048 +
         ((((d >> 4) * 64) + (((d >> 3) & 1) * 32) + (t & 31)) << 3) + (d & 7);
}

__global__ void rope_cast(const float* __restrict__ qkv,
                          const float* __restrict__ cosT, const float* __restrict__ sinT,
                          __hip_bfloat16* __restrict__ Qf,
                          __hip_bfloat16* __restrict__ Kf,
                          __hip_bfloat16* __restrict__ Vf) {
  const int QP = TOK * NH * (HD / 2);   // 2,097,152
  const int KP = TOK * NKV * (HD / 2);  //   524,288
  int idx = blockIdx.x * 256 + threadIdx.x;
  if (idx < QP) {
    int d = idx & 31, h = (idx >> 5) & 31, t = idx >> 10;
    const float* row = qkv + (size_t)t * QKVN + h * 64;
    float x1 = row[d], x2 = row[d + 32];
    float o1 = (x1 * cosT[t * 64 + d]      - x2 * sinT[t * 64 + d])      * QSCALE;
    float o2 = (x2 * cosT[t * 64 + d + 32] + x1 * sinT[t * 64 + d + 32]) * QSCALE;
    const int tile_row = h * 64 + (t >> 5);
    Qf[kq_idx(tile_row, t, d)]      = __float2bfloat16(o1);
    Qf[kq_idx(tile_row, t, d + 32)] = __float2bfloat16(o2);
  } else if (idx < QP + KP) {
    int j = idx - QP;
    int d = j & 31, hk = (j >> 5) & 7, t = j >> 8;
    const float* row = qkv + (size_t)t * QKVN + 2048 + hk * 64;
    float x1 = row[d], x2 = row[d + 32];
    float o1 = x1 * cosT[t * 64 + d]      - x2 * sinT[t * 64 + d];
    float o2 = x2 * cosT[t * 64 + d + 32] + x1 * sinT[t * 64 + d + 32];
    const int tile_row = hk * 64 + (t >> 5);
    Kf[kq_idx(tile_row, t, d)]      = __float2bfloat16(o1);
    Kf[kq_idx(tile_row, t, d + 32)] = __float2bfloat16(o2);
  } else {
    int vj = idx - QP - KP;               // d fastest -> coalesced qkv reads
    int d = vj & 63, t = (vj >> 6) & (TOK - 1), hk = vj >> 17;
    float v = qkv[(size_t)t * QKVN + 2560 + hk * 64 + d];
    const size_t tb = ((size_t)hk * 64 + (t >> 5)) * 2048;
    const int c = (((t >> 4) & 1) * 128) + ((d >> 5) * 64) + (((t >> 3) & 1) * 32) + (d & 31);
    Vf[tb + (c << 3) + (t & 7)] = __float2bfloat16(v);
  }
}

// ---------------------------------------------------------------- causal GQA flash attention
// Dual-strip waves: each block owns strip-pair (2p, 2p+1) = 64 q rows; every
// loaded KV tile feeds TWO softmax states (KV traffic halved vs R8). 4-wave
// kv-split + in-LDS merge (4 partials x 2 strips). Grid encodes bid%8 == hk
// so each XCD's L2 serves only its own K/V. compute_tile is R8's proven code.
#define MBIAS 10.0f

struct KVb { bf16x8 k0, k1, k2, k3, v00, v01, v10, v11; };

__device__ __forceinline__ void load_kv(KVb& b, const __hip_bfloat16* Kt,
                                        const __hip_bfloat16* Vt, int tile,
                                        int lane) {
  const __hip_bfloat16* Kp = Kt + (size_t)tile * 2048 + lane * 8;
  b.k0 = *reinterpret_cast<const bf16x8*>(Kp);
  b.k1 = *reinterpret_cast<const bf16x8*>(Kp + 512);
  b.k2 = *reinterpret_cast<const bf16x8*>(Kp + 1024);
  b.k3 = *reinterpret_cast<const bf16x8*>(Kp + 1536);
  const __hip_bfloat16* Vp = Vt + (size_t)tile * 2048 + lane * 8;
  b.v00 = *reinterpret_cast<const bf16x8*>(Vp);
  b.v10 = *reinterpret_cast<const bf16x8*>(Vp + 512);
  b.v01 = *reinterpret_cast<const bf16x8*>(Vp + 1024);
  b.v11 = *reinterpret_cast<const bf16x8*>(Vp + 1536);
}

__device__ __forceinline__ void compute_tile(const KVb& b, bool diag,
                                             const bf16x8 (&qf)[4],
                                             const f32x16& minit,
                                             int l31, int hi,
                                             float& mb, float& l,
                                             f32x16& oa0, f32x16& oa1) {
  // S^T = K Q^T - MBIAS (bias folded into C operand)
  __builtin_amdgcn_s_setprio(1);
  f32x16 st = __builtin_amdgcn_mfma_f32_32x32x16_bf16(b.k0, qf[0], minit, 0, 0, 0);
  st = __builtin_amdgcn_mfma_f32_32x32x16_bf16(b.k1, qf[1], st, 0, 0, 0);
  st = __builtin_amdgcn_mfma_f32_32x32x16_bf16(b.k2, qf[2], st, 0, 0, 0);
  st = __builtin_amdgcn_mfma_f32_32x32x16_bf16(b.k3, qf[3], st, 0, 0, 0);
  __builtin_amdgcn_s_setprio(0);

  float s[16];
#pragma unroll
  for (int r = 0; r < 16; ++r) s[r] = st[r];
  if (diag) {
#pragma unroll
    for (int r = 0; r < 16; ++r) {
      const int crow = (r & 3) + 8 * (r >> 2) + 4 * hi;
      s[r] = (crow <= l31) ? s[r] : -1e30f;
    }
  }
  float a0 = fmaxf(fmaxf(s[0], s[1]),  s[2]);
  float a1 = fmaxf(fmaxf(s[3], s[4]),  s[5]);
  float a2 = fmaxf(fmaxf(s[6], s[7]),  s[8]);
  float a3 = fmaxf(fmaxf(s[9], s[10]), s[11]);
  float a4 = fmaxf(fmaxf(s[12], s[13]), s[14]);
  float rmax = fmaxf(fmaxf(fmaxf(fmaxf(a0, a1), a2), fmaxf(a3, a4)), s[15]);
  rmax = fmaxf(rmax, __shfl_xor(rmax, 32));

  if (!__all(rmax <= mb + 8.0f)) {      // rescale path: ~never taken w/ this data
    const float mnew = fmaxf(mb, rmax);
    const float resc = fexp2(mb - mnew);
    l *= resc;
#pragma unroll
    for (int r = 0; r < 16; ++r) { oa0[r] *= resc; oa1[r] *= resc; }
    mb = mnew;
  }

  float p[16];
  if (mb == 0.0f) {                     // fast path: bias already folded
#pragma unroll
    for (int r = 0; r < 16; ++r) p[r] = fexp2(s[r]);
  } else {
#pragma unroll
    for (int r = 0; r < 16; ++r) p[r] = fexp2(s[r] - mb);
  }
  float u0 = (p[0] + p[1]) + (p[2] + p[3]);
  float u1 = (p[4] + p[5]) + (p[6] + p[7]);
  float u2 = (p[8] + p[9]) + (p[10] + p[11]);
  float u3 = (p[12] + p[13]) + (p[14] + p[15]);
  float rsum = (u0 + u1) + (u2 + u3);
  rsum += __shfl_xor(rsum, 32);
  l += rsum;

  unsigned int wpk[8];
#pragma unroll
  for (int j = 0; j < 8; ++j) wpk[j] = cvtpk_bf16(p[2 * j], p[2 * j + 1]);

  __builtin_amdgcn_s_setprio(1);
  {
    unsigned int x0 = wpk[0], y0 = wpk[2];  pl32swap(x0, y0);
    unsigned int x1 = wpk[1], y1 = wpk[3];  pl32swap(x1, y1);
    u32x4 pw; pw[0] = x0; pw[1] = x1; pw[2] = y0; pw[3] = y1;
    bf16x8 pf = *reinterpret_cast<bf16x8*>(&pw);
    oa0 = __builtin_amdgcn_mfma_f32_32x32x16_bf16(b.v00, pf, oa0, 0, 0, 0);
    oa1 = __builtin_amdgcn_mfma_f32_32x32x16_bf16(b.v10, pf, oa1, 0, 0, 0);
  }
  {
    unsigned int x0 = wpk[4], y0 = wpk[6];  pl32swap(x0, y0);
    unsigned int x1 = wpk[5], y1 = wpk[7];  pl32swap(x1, y1);
    u32x4 pw; pw[0] = x0; pw[1] = x1; pw[2] = y0; pw[3] = y1;
    bf16x8 pf = *reinterpret_cast<bf16x8*>(&pw);
    oa0 = __builtin_amdgcn_mfma_f32_32x32x16_bf16(b.v01, pf, oa0, 0, 0, 0);
    oa1 = __builtin_amdgcn_mfma_f32_32x32x16_bf16(b.v11, pf, oa1, 0, 0, 0);
  }
  __builtin_amdgcn_s_setprio(0);
}

// grid = 1024 blocks: idx = ((pair'*4 + hq) << 3) | hk, pair descending.
// block = 256 (4 waves = 4-way kv-split of the pair's range 0..2p+1).
__global__ __launch_bounds__(256) void attn9(const __hip_bfloat16* __restrict__ Qf,
                                             const __hip_bfloat16* __restrict__ Kf,
                                             const __hip_bfloat16* __restrict__ Vf,
                                             __hip_bfloat16* __restrict__ ctx) {
  const int idx = blockIdx.x;
  const int hk  = idx & 7;
  const int hq  = (idx >> 3) & 3;
  const int p   = 31 - (idx >> 5);             // pair, longest first
  const int h   = hk * 4 + hq;
  const int tid = threadIdx.x;
  const int w   = tid >> 6;                    // kv-split 0..3
  const int lane = tid & 63;
  const int l31  = lane & 31, hi = lane >> 5;
  const int sA = 2 * p, sB = 2 * p + 1;        // two strips, q rows [64p, 64p+64)
  const int NT = 2 * p + 2;                    // kv tiles in pair range

  __shared__ unsigned int part_u[4][2][32][33];  // [wave][strip][d0][q] bf16-packed
  __shared__ float mlb[4][2][2][32];             // [wave][strip][m/l][q]

  const __hip_bfloat16* Kt = Kf + (size_t)hk * 64 * 2048;
  const __hip_bfloat16* Vt = Vf + (size_t)hk * 64 * 2048;

  bf16x8 qfA[4], qfB[4];
  {
    const __hip_bfloat16* QpA = Qf + ((size_t)h * 64 + sA) * 2048 + lane * 8;
    const __hip_bfloat16* QpB = Qf + ((size_t)h * 64 + sB) * 2048 + lane * 8;
#pragma unroll
    for (int ks = 0; ks < 4; ++ks) {
      qfA[ks] = *reinterpret_cast<const bf16x8*>(QpA + ks * 512);
      qfB[ks] = *reinterpret_cast<const bf16x8*>(QpB + ks * 512);
    }
  }

  f32x16 minit;
#pragma unroll
  for (int r = 0; r < 16; ++r) minit[r] = -MBIAS;

  f32x16 oaA0, oaA1, oaB0, oaB1;
#pragma unroll
  for (int r = 0; r < 16; ++r) { oaA0[r] = 0.f; oaA1[r] = 0.f; oaB0[r] = 0.f; oaB1[r] = 0.f; }
  float mbA = 0.f, lA = 0.f, mbB = 0.f, lB = 0.f;

  if (w < NT) {                                // wave-uniform
    KVb b0, b1;
    load_kv(b0, Kt, Vt, w, lane);
    int t = w;
    for (;;) {
      int nx = t + 4;
      if (nx < NT) load_kv(b1, Kt, Vt, nx, lane);
      if (t <= sA) compute_tile(b0, t == sA, qfA, minit, l31, hi, mbA, lA, oaA0, oaA1);
      compute_tile(b0, t == sB, qfB, minit, l31, hi, mbB, lB, oaB0, oaB1);
      t = nx;
      if (t >= NT) break;
      nx = t + 4;
      if (nx < NT) load_kv(b0, Kt, Vt, nx, lane);
      if (t <= sA) compute_tile(b1, t == sA, qfA, minit, l31, hi, mbA, lA, oaA0, oaA1);
      compute_tile(b1, t == sB, qfB, minit, l31, hi, mbB, lB, oaB0, oaB1);
      t = nx;
      if (t >= NT) break;
    }
  }

  // ---- partials to LDS (bf16-packed); idle waves contribute l=0 (harmless)
#pragma unroll
  for (int r = 0; r < 16; ++r) {
    const int d0 = (r & 3) + 8 * (r >> 2) + 4 * hi;   // 0..31
    part_u[w][0][d0][l31] = cvtpk_bf16(oaA0[r], oaA1[r]);
    part_u[w][1][d0][l31] = cvtpk_bf16(oaB0[r], oaB1[r]);
  }
  if (hi == 0) {
    mlb[w][0][0][l31] = mbA; mlb[w][0][1][l31] = lA;
    mlb[w][1][0][l31] = mbB; mlb[w][1][1][l31] = lB;
  }
  __syncthreads();

  // ---- merge 4 partials per strip + write ctx (lanes span d; coalesced)
  const int d  = tid & 63;
  const int qg = tid >> 6;                     // 0..3 -> 16 (strip,q) slots each
#pragma unroll
  for (int qq = 0; qq < 16; ++qq) {
    const int Xq = qg * 16 + qq;               // 0..63
    const int X  = Xq >> 5;                    // strip 0=A,1=B
    const int q  = Xq & 31;
    const float m0 = mlb[0][X][0][q], m1 = mlb[1][X][0][q];
    const float m2 = mlb[2][X][0][q], m3 = mlb[3][X][0][q];
    const float M = fmaxf(fmaxf(m0, m1), fmaxf(m2, m3));
    const float s0 = fexp2(m0 - M), s1 = fexp2(m1 - M);
    const float s2 = fexp2(m2 - M), s3 = fexp2(m3 - M);
    const float L = mlb[0][X][1][q] * s0 + mlb[1][X][1][q] * s1 +
                    mlb[2][X][1][q] * s2 + mlb[3][X][1][q] * s3;
    const unsigned int u0 = part_u[0][X][d & 31][q];
    const unsigned int u1 = part_u[1][X][d & 31][q];
    const unsigned int u2 = part_u[2][X][d & 31][q];
    const unsigned int u3 = part_u[3][X][d & 31][q];
    const unsigned int msk = (d < 32) ? 0u : 0xffff0000u;
    const int sh = (d < 32) ? 16 : 0;
    const float p0 = __uint_as_float((u0 << sh) & (msk | 0xffff0000u));
    const float p1 = __uint_as_float((u1 << sh) & (msk | 0xffff0000u));
    const float p2 = __uint_as_float((u2 << sh) & (msk | 0xffff0000u));
    const float p3 = __uint_as_float((u3 << sh) & (msk | 0xffff0000u));
    const float val = p0 * s0 + p1 * s1 + p2 * s2 + p3 * s3;
    const int row = 64 * p + X * 32 + q;
    ctx[(size_t)row * EMB + h * HD + d] = __float2bfloat16(val / L);
  }
}

// ---------------------------------------------------------------- launch
extern "C" void kernel_launch(void* const* d_in, const int* in_sizes, int n_in,
                              void* d_out, int out_size, void* d_ws, size_t ws_size,
                              hipStream_t stream) {
  const float* x    = (const float*)d_in[0];
  const float* cosT = (const float*)d_in[1];
  const float* sinT = (const float*)d_in[2];
  const float* Wq   = (const float*)d_in[3];
  const float* Wk   = (const float*)d_in[4];
  const float* Wv   = (const float*)d_in[5];
  const float* Wo   = (const float*)d_in[6];
  float* out = (float*)d_out;

  const size_t M4 = (size_t)4 * 1024 * 1024;
  const size_t M1 = (size_t)1024 * 1024;

  char* ws = (char*)d_ws;
  __hip_bfloat16* xb   = (__hip_bfloat16*)ws;
  __hip_bfloat16* Wc   = xb + M4;
  __hip_bfloat16* Wob  = Wc + (size_t)6 * M1;
  float*          qkv  = (float*)(Wob + M4);
  __hip_bfloat16* Qf   = (__hip_bfloat16*)(qkv + (size_t)TOK * QKVN);
  __hip_bfloat16* Kf   = Qf + (size_t)NH * TOK * HD;
  __hip_bfloat16* Vf   = Kf + (size_t)NKV * TOK * HD;
  __hip_bfloat16* ctxb = Vf + (size_t)NKV * HD * TOK;

  constexpr int SLOT192 = 128 * 128 + 192 * 128;
  constexpr int SLOT128 = 128 * 128 + 128 * 128;
  hipFuncSetAttribute(reinterpret_cast<const void*>(&gemm8<192>),
                      hipFuncAttributeMaxDynamicSharedMemorySize, 3 * SLOT192);
  hipFuncSetAttribute(reinterpret_cast<const void*>(&gemm8<128>),
                      hipFuncAttributeMaxDynamicSharedMemorySize, 3 * SLOT128);

  cast_all<<<14336, 256, 0, stream>>>(x, Wq, Wk, Wv, Wo, xb, Wc, Wob);

  // qkv = x @ Wqkv^T   (M=2048, N=3072, K=2048): 256 blocks
  gemm8<192><<<256, 512, 3 * SLOT192, stream>>>(xb, Wc, qkv, TOK, QKVN, EMB);

  rope_cast<<<14336, 256, 0, stream>>>(qkv, cosT, sinT, Qf, Kf, Vf);

  // causal GQA attention: dual-strip pair blocks, hk-locality grid, 4-way split
  attn9<<<1024, 256, 0, stream>>>(Qf, Kf, Vf, ctxb);

  // out = ctx @ Wo^T   (M=N=K=2048): 256 blocks
  gemm8<128><<<256, 512, 3 * SLOT128, stream>>>(ctxb, Wob, out, TOK, EMB, EMB);
}

// Round 12
// 120.461 us; speedup vs baseline: 1.4344x; 1.1953x over previous
//
#include <hip/hip_runtime.h>
#include <hip/hip_bf16.h>
#include <stdint.h>

#define EMB   2048
#define TOK   2048
#define NH    32
#define NKV   8
#define HD    64
#define QKVN  3072   // 2048 q + 512 k + 512 v

typedef __attribute__((ext_vector_type(8))) short bf16x8;   // 8 bf16 = 4 VGPRs
typedef __attribute__((ext_vector_type(4))) float f32x4;
typedef __attribute__((ext_vector_type(16))) float f32x16;
typedef __attribute__((ext_vector_type(4))) unsigned int u32x4;

__device__ __forceinline__ void gld16(const void* g, void* l) {
  auto gp = reinterpret_cast<const int __attribute__((address_space(1)))*>(
      reinterpret_cast<uintptr_t>(g));
  auto lp = reinterpret_cast<int __attribute__((address_space(3)))*>(
      reinterpret_cast<uintptr_t>(l));
  __builtin_amdgcn_global_load_lds(gp, lp, 16, 0, 0);
}

__device__ __forceinline__ unsigned int cvtpk_bf16(float lo, float hi) {
  unsigned int r;
  asm("v_cvt_pk_bf16_f32 %0, %1, %2" : "=v"(r) : "v"(lo), "v"(hi));
  return r;
}
// v_permlane32_swap_b32 — only ever used with distinct-value operands (P-relayout).
__device__ __forceinline__ void pl32swap(unsigned int &a, unsigned int &b) {
  asm volatile("v_permlane32_swap_b32 %0, %1" : "+v"(a), "+v"(b));
}
__device__ __forceinline__ float fexp2(float x) {  // v_exp_f32 IS 2^x
  float r;
  asm("v_exp_f32 %0, %1" : "=v"(r) : "v"(x));
  return r;
}

// ---------------------------------------------------------------- cast fp32->bf16
__global__ void cast_all(const float* __restrict__ x,  const float* __restrict__ wq,
                         const float* __restrict__ wk, const float* __restrict__ wv,
                         const float* __restrict__ wo,
                         __hip_bfloat16* __restrict__ xb,
                         __hip_bfloat16* __restrict__ wc,
                         __hip_bfloat16* __restrict__ wob) {
  const size_t M4 = (size_t)4 * 1024 * 1024;
  const size_t M1 = (size_t)1024 * 1024;
  size_t i = ((size_t)blockIdx.x * 256 + threadIdx.x) * 4;
  const float* src;
  __hip_bfloat16* dst;
  if (i < M4)                    { src = x  + i;                 dst = xb  + i; }
  else if (i < 2*M4)             { src = wq + (i - M4);          dst = wc  + (i - M4); }
  else if (i < 2*M4 + M1)        { src = wk + (i - 2*M4);        dst = wc  + M4 + (i - 2*M4); }
  else if (i < 2*M4 + 2*M1)      { src = wv + (i - 2*M4 - M1);   dst = wc  + M4 + M1 + (i - 2*M4 - M1); }
  else                           { src = wo + (i - 2*M4 - 2*M1); dst = wob + (i - 2*M4 - 2*M1); }
  float4 v = *reinterpret_cast<const float4*>(src);
  dst[0] = __float2bfloat16(v.x);
  dst[1] = __float2bfloat16(v.y);
  dst[2] = __float2bfloat16(v.z);
  dst[3] = __float2bfloat16(v.w);
}

// ---------------------------------------------------------------- GEMM  C = A * B^T
// Counted-vmcnt 3-slot schedule (T3+T4), (row&7)<<4 XOR swizzle (T2), 8 waves.
// OT = output type (float or __hip_bfloat16).
template<int BN, typename OT>
__global__ __launch_bounds__(512) void gemm8(const __hip_bfloat16* __restrict__ A,
                                             const __hip_bfloat16* __restrict__ B,
                                             OT* __restrict__ C,
                                             int M, int N, int K) {
  constexpr int A_BYTES = 128 * 128;        // 16 KB
  constexpr int B_BYTES = BN * 128;
  constexpr int SLOT    = A_BYTES + B_BYTES;
  constexpr int CA = 2;
  constexpr int CB = BN / 64;
  constexpr int NR = BN / 64;
  extern __shared__ char lds[];             // 3 * SLOT

  const int nbc = N / BN;
  const int nwg = gridDim.x;
  int bid = blockIdx.x;
  bid = (bid & 7) * (nwg >> 3) + (bid >> 3);   // bijective XCD swizzle
  const int br = bid / nbc, bc = bid % nbc;

  const int tid  = threadIdx.x;
  const int w    = tid >> 6;
  const int lane = tid & 63;
  const int wr   = w >> 2, wc = w & 3;
  const int l15  = lane & 15, lg = lane >> 4;
  const int axor = (l15 & 7) << 4;

  const __hip_bfloat16* Ag = A + (size_t)br * 128 * K;
  const __hip_bfloat16* Bg = B + (size_t)bc * BN * K;

  const int srow = lane >> 3;
  const int scol = (((lane & 7) ^ srow) << 3);

  auto stageA = [&](char* slot, int kt) {
#pragma unroll
    for (int i = 0; i < CA; ++i) {
      const int c = w * CA + i;
      gld16(Ag + (size_t)(c * 8 + srow) * K + kt + scol, slot + c * 1024);
    }
  };
  auto stageB = [&](char* slot, int kt) {
#pragma unroll
    for (int i = 0; i < CB; ++i) {
      const int c = w * CB + i;
      gld16(Bg + (size_t)(c * 8 + srow) * K + kt + scol, slot + A_BYTES + c * 1024);
    }
  };
  auto ldA = [&](const char* sa, int m, int kk) {
    return *reinterpret_cast<const bf16x8*>(
        sa + (wr * 64 + m * 16 + l15) * 128 + ((kk * 64 + lg * 16) ^ axor));
  };
  auto ldB = [&](const char* sa, int n, int kk) {
    return *reinterpret_cast<const bf16x8*>(
        sa + A_BYTES + (wc * (BN / 4) + n * 16 + l15) * 128 + ((kk * 64 + lg * 16) ^ axor));
  };

  f32x4 acc[4][NR];
#pragma unroll
  for (int m = 0; m < 4; ++m)
#pragma unroll
    for (int n = 0; n < NR; ++n) acc[m][n] = (f32x4){0.f, 0.f, 0.f, 0.f};

  const int nt = K >> 6;

  stageA(lds, 0);         stageB(lds, 0);
  stageA(lds + SLOT, 64); stageB(lds + SLOT, 64);
  if constexpr (CA + CB == 4) asm volatile("s_waitcnt vmcnt(4)" ::: "memory");
  else                        asm volatile("s_waitcnt vmcnt(5)" ::: "memory");
  __builtin_amdgcn_s_barrier();

  int slc = 0, sls = 2;
  for (int t = 0; t < nt; ++t) {
    const char* sa = lds + slc * SLOT;
    char* stg = lds + sls * SLOT;
    const bool do_stage = (t + 2) < nt;
    const int kt2 = (t + 2) << 6;

    bf16x8 afr[2][2], bfr[NR][2];
#pragma unroll
    for (int m = 0; m < 2; ++m)
#pragma unroll
      for (int kk = 0; kk < 2; ++kk) afr[m][kk] = ldA(sa, m, kk);
#pragma unroll
    for (int n = 0; n < NR; ++n)
#pragma unroll
      for (int kk = 0; kk < 2; ++kk) bfr[n][kk] = ldB(sa, n, kk);
    if (do_stage) stageA(stg, kt2);
    __builtin_amdgcn_s_barrier();
    asm volatile("s_waitcnt lgkmcnt(0)" ::: "memory");
    __builtin_amdgcn_sched_barrier(0);
    __builtin_amdgcn_s_setprio(1);
#pragma unroll
    for (int m = 0; m < 2; ++m)
#pragma unroll
      for (int n = 0; n < NR; ++n)
#pragma unroll
        for (int kk = 0; kk < 2; ++kk)
          acc[m][n] = __builtin_amdgcn_mfma_f32_16x16x32_bf16(afr[m][kk], bfr[n][kk],
                                                              acc[m][n], 0, 0, 0);
    __builtin_amdgcn_s_setprio(0);
    __builtin_amdgcn_s_barrier();

#pragma unroll
    for (int m = 0; m < 2; ++m)
#pragma unroll
      for (int kk = 0; kk < 2; ++kk) afr[m][kk] = ldA(sa, 2 + m, kk);
    if (do_stage) stageB(stg, kt2);
    __builtin_amdgcn_s_barrier();
    asm volatile("s_waitcnt lgkmcnt(0)" ::: "memory");
    __builtin_amdgcn_sched_barrier(0);
    __builtin_amdgcn_s_setprio(1);
#pragma unroll
    for (int m = 0; m < 2; ++m)
#pragma unroll
      for (int n = 0; n < NR; ++n)
#pragma unroll
        for (int kk = 0; kk < 2; ++kk)
          acc[2 + m][n] = __builtin_amdgcn_mfma_f32_16x16x32_bf16(afr[m][kk], bfr[n][kk],
                                                                  acc[2 + m][n], 0, 0, 0);
    __builtin_amdgcn_s_setprio(0);
    if (t < nt - 2) {
      if constexpr (CA + CB == 4) asm volatile("s_waitcnt vmcnt(4)" ::: "memory");
      else                        asm volatile("s_waitcnt vmcnt(5)" ::: "memory");
    } else {
      asm volatile("s_waitcnt vmcnt(0)" ::: "memory");
    }
    __builtin_amdgcn_s_barrier();

    slc = (slc == 2) ? 0 : slc + 1;
    sls = (sls == 2) ? 0 : sls + 1;
  }

  const int row0 = br * 128 + wr * 64;
  const int col0 = bc * BN + wc * (BN / 4);
#pragma unroll
  for (int m = 0; m < 4; ++m)
#pragma unroll
    for (int n = 0; n < NR; ++n)
#pragma unroll
      for (int r = 0; r < 4; ++r) {
        const size_t off = (size_t)(row0 + m * 16 + lg * 4 + r) * N + col0 + n * 16 + l15;
        if constexpr (sizeof(OT) == 4) C[off] = acc[m][n][r];
        else                           C[off] = __float2bfloat16(acc[m][n][r]);
      }
}

// ---------------------------------------------------------------- RoPE + cast to tiled fragment layouts
// qkv input is now bf16 (written directly by gemm1) — halves this kernel's reads.
#define QSCALE 0.1803368801111243f   // 0.125 * log2(e)

__device__ __forceinline__ size_t kq_idx(int tile_row, int t, int d) {
  return ((size_t)tile_row) * 2048 +
         ((((d >> 4) * 64) + (((d >> 3) & 1) * 32) + (t & 31)) << 3) + (d & 7);
}

__global__ void rope_cast(const __hip_bfloat16* __restrict__ qkv,
                          const float* __restrict__ cosT, const float* __restrict__ sinT,
                          __hip_bfloat16* __restrict__ Qf,
                          __hip_bfloat16* __restrict__ Kf,
                          __hip_bfloat16* __restrict__ Vf) {
  const int QP = TOK * NH * (HD / 2);   // 2,097,152
  const int KP = TOK * NKV * (HD / 2);  //   524,288
  int idx = blockIdx.x * 256 + threadIdx.x;
  if (idx < QP) {
    int d = idx & 31, h = (idx >> 5) & 31, t = idx >> 10;
    const __hip_bfloat16* row = qkv + (size_t)t * QKVN + h * 64;
    float x1 = __bfloat162float(row[d]), x2 = __bfloat162float(row[d + 32]);
    float o1 = (x1 * cosT[t * 64 + d]      - x2 * sinT[t * 64 + d])      * QSCALE;
    float o2 = (x2 * cosT[t * 64 + d + 32] + x1 * sinT[t * 64 + d + 32]) * QSCALE;
    const int tile_row = h * 64 + (t >> 5);
    Qf[kq_idx(tile_row, t, d)]      = __float2bfloat16(o1);
    Qf[kq_idx(tile_row, t, d + 32)] = __float2bfloat16(o2);
  } else if (idx < QP + KP) {
    int j = idx - QP;
    int d = j & 31, hk = (j >> 5) & 7, t = j >> 8;
    const __hip_bfloat16* row = qkv + (size_t)t * QKVN + 2048 + hk * 64;
    float x1 = __bfloat162float(row[d]), x2 = __bfloat162float(row[d + 32]);
    float o1 = x1 * cosT[t * 64 + d]      - x2 * sinT[t * 64 + d];
    float o2 = x2 * cosT[t * 64 + d + 32] + x1 * sinT[t * 64 + d + 32];
    const int tile_row = hk * 64 + (t >> 5);
    Kf[kq_idx(tile_row, t, d)]      = __float2bfloat16(o1);
    Kf[kq_idx(tile_row, t, d + 32)] = __float2bfloat16(o2);
  } else {
    int vj = idx - QP - KP;               // d fastest -> coalesced qkv reads
    int d = vj & 63, t = (vj >> 6) & (TOK - 1), hk = vj >> 17;
    const __hip_bfloat16 v = qkv[(size_t)t * QKVN + 2560 + hk * 64 + d];
    const size_t tb = ((size_t)hk * 64 + (t >> 5)) * 2048;
    const int c = (((t >> 4) & 1) * 128) + ((d >> 5) * 64) + (((t >> 3) & 1) * 32) + (d & 31);
    Vf[tb + (c << 3) + (t & 7)] = v;
  }
}

// ---------------------------------------------------------------- causal GQA flash attention
// EXACT R8 attn6 structure/schedule; ONLY the grid decode changed: consecutive
// blockIdx cycles hk (idx&7) so round-robin XCD dispatch gives XCD j only
// kv-head j's K/V (512 KB -> L2-resident, re-reads served from L2 not L3).
#define MBIAS 10.0f

struct KVb { bf16x8 k0, k1, k2, k3, v00, v01, v10, v11; };

__device__ __forceinline__ void load_kv(KVb& b, const __hip_bfloat16* Kt,
                                        const __hip_bfloat16* Vt, int tile,
                                        int lane) {
  const __hip_bfloat16* Kp = Kt + (size_t)tile * 2048 + lane * 8;
  b.k0 = *reinterpret_cast<const bf16x8*>(Kp);
  b.k1 = *reinterpret_cast<const bf16x8*>(Kp + 512);
  b.k2 = *reinterpret_cast<const bf16x8*>(Kp + 1024);
  b.k3 = *reinterpret_cast<const bf16x8*>(Kp + 1536);
  const __hip_bfloat16* Vp = Vt + (size_t)tile * 2048 + lane * 8;
  b.v00 = *reinterpret_cast<const bf16x8*>(Vp);
  b.v10 = *reinterpret_cast<const bf16x8*>(Vp + 512);
  b.v01 = *reinterpret_cast<const bf16x8*>(Vp + 1024);
  b.v11 = *reinterpret_cast<const bf16x8*>(Vp + 1536);
}

__device__ __forceinline__ void compute_tile(const KVb& b, bool diag,
                                             const bf16x8 (&qf)[4],
                                             const f32x16& minit,
                                             int l31, int hi,
                                             float& mb, float& l,
                                             f32x16& oa0, f32x16& oa1) {
  // S^T = K Q^T - MBIAS (bias folded into C operand)
  __builtin_amdgcn_s_setprio(1);
  f32x16 st = __builtin_amdgcn_mfma_f32_32x32x16_bf16(b.k0, qf[0], minit, 0, 0, 0);
  st = __builtin_amdgcn_mfma_f32_32x32x16_bf16(b.k1, qf[1], st, 0, 0, 0);
  st = __builtin_amdgcn_mfma_f32_32x32x16_bf16(b.k2, qf[2], st, 0, 0, 0);
  st = __builtin_amdgcn_mfma_f32_32x32x16_bf16(b.k3, qf[3], st, 0, 0, 0);
  __builtin_amdgcn_s_setprio(0);

  float s[16];
#pragma unroll
  for (int r = 0; r < 16; ++r) s[r] = st[r];
  if (diag) {
#pragma unroll
    for (int r = 0; r < 16; ++r) {
      const int crow = (r & 3) + 8 * (r >> 2) + 4 * hi;
      s[r] = (crow <= l31) ? s[r] : -1e30f;
    }
  }
  float a0 = fmaxf(fmaxf(s[0], s[1]),  s[2]);
  float a1 = fmaxf(fmaxf(s[3], s[4]),  s[5]);
  float a2 = fmaxf(fmaxf(s[6], s[7]),  s[8]);
  float a3 = fmaxf(fmaxf(s[9], s[10]), s[11]);
  float a4 = fmaxf(fmaxf(s[12], s[13]), s[14]);
  float rmax = fmaxf(fmaxf(fmaxf(fmaxf(a0, a1), a2), fmaxf(a3, a4)), s[15]);
  rmax = fmaxf(rmax, __shfl_xor(rmax, 32));

  if (!__all(rmax <= mb + 8.0f)) {      // rescale path: ~never taken w/ this data
    const float mnew = fmaxf(mb, rmax);
    const float resc = fexp2(mb - mnew);
    l *= resc;
#pragma unroll
    for (int r = 0; r < 16; ++r) { oa0[r] *= resc; oa1[r] *= resc; }
    mb = mnew;
  }

  float p[16];
  if (mb == 0.0f) {                     // fast path: bias already folded
#pragma unroll
    for (int r = 0; r < 16; ++r) p[r] = fexp2(s[r]);
  } else {
#pragma unroll
    for (int r = 0; r < 16; ++r) p[r] = fexp2(s[r] - mb);
  }
  float u0 = (p[0] + p[1]) + (p[2] + p[3]);
  float u1 = (p[4] + p[5]) + (p[6] + p[7]);
  float u2 = (p[8] + p[9]) + (p[10] + p[11]);
  float u3 = (p[12] + p[13]) + (p[14] + p[15]);
  float rsum = (u0 + u1) + (u2 + u3);
  rsum += __shfl_xor(rsum, 32);
  l += rsum;

  unsigned int wpk[8];
#pragma unroll
  for (int j = 0; j < 8; ++j) wpk[j] = cvtpk_bf16(p[2 * j], p[2 * j + 1]);

  __builtin_amdgcn_s_setprio(1);
  {
    unsigned int x0 = wpk[0], y0 = wpk[2];  pl32swap(x0, y0);
    unsigned int x1 = wpk[1], y1 = wpk[3];  pl32swap(x1, y1);
    u32x4 pw; pw[0] = x0; pw[1] = x1; pw[2] = y0; pw[3] = y1;
    bf16x8 pf = *reinterpret_cast<bf16x8*>(&pw);
    oa0 = __builtin_amdgcn_mfma_f32_32x32x16_bf16(b.v00, pf, oa0, 0, 0, 0);
    oa1 = __builtin_amdgcn_mfma_f32_32x32x16_bf16(b.v10, pf, oa1, 0, 0, 0);
  }
  {
    unsigned int x0 = wpk[4], y0 = wpk[6];  pl32swap(x0, y0);
    unsigned int x1 = wpk[5], y1 = wpk[7];  pl32swap(x1, y1);
    u32x4 pw; pw[0] = x0; pw[1] = x1; pw[2] = y0; pw[3] = y1;
    bf16x8 pf = *reinterpret_cast<bf16x8*>(&pw);
    oa0 = __builtin_amdgcn_mfma_f32_32x32x16_bf16(b.v01, pf, oa0, 0, 0, 0);
    oa1 = __builtin_amdgcn_mfma_f32_32x32x16_bf16(b.v11, pf, oa1, 0, 0, 0);
  }
  __builtin_amdgcn_s_setprio(0);
}

// grid = 2048: idx = ((strip'*4 + hq) << 3) | hk  (hk fastest -> XCD affinity,
// strip' ascending = strip descending -> longest first). block = 128 (2 waves).
__global__ __launch_bounds__(128) void attn6(const __hip_bfloat16* __restrict__ Qf,
                                             const __hip_bfloat16* __restrict__ Kf,
                                             const __hip_bfloat16* __restrict__ Vf,
                                             __hip_bfloat16* __restrict__ ctx) {
  const int idx   = blockIdx.x;
  const int hk    = idx & 7;
  const int hq    = (idx >> 3) & 3;
  const int strip = 63 - (idx >> 5);
  const int h     = hk * 4 + hq;
  const int tid   = threadIdx.x;
  const int w     = tid >> 6;                  // kv-split 0..1
  const int lane  = tid & 63;
  const int l31   = lane & 31, hi = lane >> 5;
  const int q0    = strip * 32;
  const int nt    = strip + 1;

  __shared__ unsigned int part_u[2][32][33];   // packed bf16 (lo=d, hi=d+32)
  __shared__ float mlb[2][2][32];

  const __hip_bfloat16* Kt = Kf + (size_t)hk * 64 * 2048;
  const __hip_bfloat16* Vt = Vf + (size_t)hk * 64 * 2048;

  const __hip_bfloat16* Qp = Qf + ((size_t)h * 64 + strip) * 2048 + lane * 8;
  bf16x8 qf[4];
#pragma unroll
  for (int ks = 0; ks < 4; ++ks)
    qf[ks] = *reinterpret_cast<const bf16x8*>(Qp + ks * 512);

  f32x16 minit;
#pragma unroll
  for (int r = 0; r < 16; ++r) minit[r] = -MBIAS;

  f32x16 oa0, oa1;
#pragma unroll
  for (int r = 0; r < 16; ++r) { oa0[r] = 0.f; oa1[r] = 0.f; }
  float mb = 0.f, l = 0.f;

  if (w < nt) {                                // wave-uniform
    KVb A, B;
    load_kv(A, Kt, Vt, w, lane);
    int t = w;
    for (;;) {
      int nx = t + 2;
      if (nx < nt) load_kv(B, Kt, Vt, nx, lane);
      compute_tile(A, t == nt - 1, qf, minit, l31, hi, mb, l, oa0, oa1);
      t = nx;
      if (t >= nt) break;
      nx = t + 2;
      if (nx < nt) load_kv(A, Kt, Vt, nx, lane);
      compute_tile(B, t == nt - 1, qf, minit, l31, hi, mb, l, oa0, oa1);
      t = nx;
      if (t >= nt) break;
    }
  }

  // ---- partials to LDS (bf16-packed); mb values share the same -MBIAS offset,
  // which cancels in the merge.
#pragma unroll
  for (int r = 0; r < 16; ++r) {
    const int d0 = (r & 3) + 8 * (r >> 2) + 4 * hi;   // 0..31
    part_u[w][d0][l31] = cvtpk_bf16(oa0[r], oa1[r]);
  }
  if (hi == 0) { mlb[w][0][l31] = mb; mlb[w][1][l31] = l; }
  __syncthreads();

  // ---- merge 2 partials + write ctx (coalesced: lanes span d)
  const int d  = tid & 63;
  const int qg = tid >> 6;
#pragma unroll
  for (int qq = 0; qq < 16; ++qq) {
    const int q = qg * 16 + qq;
    const float m0 = mlb[0][0][q], m1 = mlb[1][0][q];
    const float M = fmaxf(m0, m1);
    const float s0 = fexp2(m0 - M), s1 = fexp2(m1 - M);
    const float L = mlb[0][1][q] * s0 + mlb[1][1][q] * s1;
    const unsigned int u0 = part_u[0][d & 31][q];
    const unsigned int u1 = part_u[1][d & 31][q];
    const unsigned int w0 = (d < 32) ? (u0 << 16) : (u0 & 0xffff0000u);
    const unsigned int w1 = (d < 32) ? (u1 << 16) : (u1 & 0xffff0000u);
    const float p0 = __uint_as_float(w0), p1 = __uint_as_float(w1);
    ctx[(size_t)(q0 + q) * EMB + h * HD + d] = __float2bfloat16((p0 * s0 + p1 * s1) / L);
  }
}

// ---------------------------------------------------------------- launch
extern "C" void kernel_launch(void* const* d_in, const int* in_sizes, int n_in,
                              void* d_out, int out_size, void* d_ws, size_t ws_size,
                              hipStream_t stream) {
  const float* x    = (const float*)d_in[0];
  const float* cosT = (const float*)d_in[1];
  const float* sinT = (const float*)d_in[2];
  const float* Wq   = (const float*)d_in[3];
  const float* Wk   = (const float*)d_in[4];
  const float* Wv   = (const float*)d_in[5];
  const float* Wo   = (const float*)d_in[6];
  float* out = (float*)d_out;

  const size_t M4 = (size_t)4 * 1024 * 1024;
  const size_t M1 = (size_t)1024 * 1024;

  char* ws = (char*)d_ws;
  __hip_bfloat16* xb   = (__hip_bfloat16*)ws;
  __hip_bfloat16* Wc   = xb + M4;
  __hip_bfloat16* Wob  = Wc + (size_t)6 * M1;
  __hip_bfloat16* qkvb = Wob + M4;                    // bf16 qkv (12 MB)
  __hip_bfloat16* Qf   = qkvb + (size_t)TOK * QKVN;
  __hip_bfloat16* Kf   = Qf + (size_t)NH * TOK * HD;
  __hip_bfloat16* Vf   = Kf + (size_t)NKV * TOK * HD;
  __hip_bfloat16* ctxb = Vf + (size_t)NKV * HD * TOK;

  constexpr int SLOT192 = 128 * 128 + 192 * 128;
  constexpr int SLOT128 = 128 * 128 + 128 * 128;
  hipFuncSetAttribute(reinterpret_cast<const void*>(&gemm8<192, __hip_bfloat16>),
                      hipFuncAttributeMaxDynamicSharedMemorySize, 3 * SLOT192);
  hipFuncSetAttribute(reinterpret_cast<const void*>(&gemm8<128, float>),
                      hipFuncAttributeMaxDynamicSharedMemorySize, 3 * SLOT128);

  cast_all<<<14336, 256, 0, stream>>>(x, Wq, Wk, Wv, Wo, xb, Wc, Wob);

  // qkv = x @ Wqkv^T (M=2048, N=3072, K=2048), bf16 out: 256 blocks
  gemm8<192, __hip_bfloat16><<<256, 512, 3 * SLOT192, stream>>>(xb, Wc, qkvb,
                                                                TOK, QKVN, EMB);

  rope_cast<<<14336, 256, 0, stream>>>(qkvb, cosT, sinT, Qf, Kf, Vf);

  // causal GQA attention: R8 structure + hk->XCD affinity grid
  attn6<<<64 * 32, 128, 0, stream>>>(Qf, Kf, Vf, ctxb);

  // out = ctx @ Wo^T (M=N=K=2048), fp32 out: 256 blocks
  gemm8<128, float><<<256, 512, 3 * SLOT128, stream>>>(ctxb, Wob, out, TOK, EMB, EMB);
}